// Round 3
// baseline (384.836 us; speedup 1.0000x reference)
//
#include <hip/hip_runtime.h>

// KernelAggregation: per-sample mixed 3x3 SAME conv, implicit GEMM via bf16 MFMA.
// ws layout: [0, 2359296) = wmix bf16, fragment-major [32 b][9 tap][2 s][4 mt][64 lane][8 j];
//            [2359296, +8192) = bmix f32 [32][64].

#define DIM 64
#define BATCH 32
#define HH 128
#define WW 128
#define NK 4

typedef __attribute__((ext_vector_type(4))) float f32x4;
typedef __attribute__((ext_vector_type(8))) short bf16x8;
typedef __attribute__((ext_vector_type(2))) unsigned int u32x2;

static __device__ __forceinline__ unsigned short f2bf(float f) {
    union { float f; unsigned u; } v; v.f = f;
    unsigned r = v.u + 0x7fffu + ((v.u >> 16) & 1u);   // RNE, inputs finite
    return (unsigned short)(r >> 16);
}
static __device__ __forceinline__ unsigned pack2(float a, float b) {
    union { float f; unsigned u; } va, vb; va.f = a; vb.f = b;
    unsigned ra = (va.u + 0x7fffu + ((va.u >> 16) & 1u)) >> 16;
    unsigned rb = (vb.u + 0x7fffu + ((vb.u >> 16) & 1u)) >> 16;
    return ra | (rb << 16);
}

// One wave per (b, co): coalesced read of w[k][co][ci][kh][kw], mix over k in
// registers, LDS transpose (ci,tap)->(tap,ci), scatter into fragment-major wmix:
//   element (co, ci, tap) -> [tap][s=ci>>5][mt=co>>4][lane=((ci>>3)&3)<<4|(co&15)][j=ci&7]
__global__ __launch_bounds__(256) void mix_weights(
    const float* __restrict__ w, const float* __restrict__ att,
    unsigned short* __restrict__ wmix) {
    __shared__ float tr[4][576];
    int wave = threadIdx.x >> 6, lane = threadIdx.x & 63;
    int idx = blockIdx.x * 4 + wave;               // 2048 (b,co) pairs
    int b = idx >> 6, co = idx & 63;
    float a[NK];
    #pragma unroll
    for (int k = 0; k < NK; ++k) a[k] = att[b * NK + k];
    float s[9];
    #pragma unroll
    for (int t = 0; t < 9; ++t) s[t] = 0.f;
    #pragma unroll
    for (int k = 0; k < NK; ++k) {
        const float* wp = w + (size_t)(k * DIM + co) * 576;
        #pragma unroll
        for (int t = 0; t < 9; ++t)
            s[t] += a[k] * wp[t * 64 + lane];      // element e = t*64+lane = ci*9+tap
    }
    #pragma unroll
    for (int t = 0; t < 9; ++t) tr[wave][t * 64 + lane] = s[t];
    __syncthreads();
    int mt = co >> 4;
    int lo = ((lane >> 3) & 3) * 16 + (co & 15);   // fragment lane
    int ss = lane >> 5;
    int jj = lane & 7;
    #pragma unroll
    for (int t = 0; t < 9; ++t) {
        float v = tr[wave][lane * 9 + t];
        wmix[(size_t)((((b * 9 + t) * 2 + ss) * 4 + mt) * 64 + lo) * 8 + jj] = f2bf(v);
    }
}

__global__ __launch_bounds__(256) void mix_bias(
    const float* __restrict__ bias, const float* __restrict__ att,
    float* __restrict__ bmix) {
    int idx = blockIdx.x * 256 + threadIdx.x;      // 2048
    if (idx >= BATCH * DIM) return;
    int b = idx >> 6, co = idx & 63;
    float s = 0.f;
    for (int k = 0; k < NK; ++k) s += att[b * NK + k] * bias[k * DIM + co];
    bmix[idx] = s;
}

// Persistent rolling-row blocks: 512 blocks = 2/CU exactly (no tail). Block =
// (b, w-half, 16-row chunk) -> 4 tiles of 4 output rows. Xs = 8-row RING
// [slot][66][64] bf16 (67,584 B). Per tile: issue next-4-rows loads BEFORE the
// 18 MFMA steps; rows +5,+6 go to ring slots free during compute (written
// mid-loop, no barrier); rows +7,+8 after barrier 1; barrier 2; stores after
// (drain hides under next compute). A-fragments stream from L2 via ring-3.
__global__ __launch_bounds__(256, 2) void conv_mfma(
    const float* __restrict__ x, const unsigned short* __restrict__ wmix,
    const float* __restrict__ bmix, float* __restrict__ out) {

    __shared__ unsigned short Xs[8 * 66 * 64];     // 67,584 B

    int bid = blockIdx.x;
    bid = (bid & 7) * 64 + (bid >> 3);             // XCD-contiguous remap (512 = 8*64)
    int b  = bid >> 4;                             // 16 blocks per sample on one XCD
    int wh = (bid >> 3) & 1;
    int ch = bid & 7;
    int h0 = ch * 16, w0 = wh * 64;

    int tid  = threadIdx.x;
    int wave = tid >> 6, lane = tid & 63;
    int l15  = lane & 15, q = lane >> 4;
    int cq   = tid >> 4, c4 = tid & 15;            // ci-quad, col-quad for staging

    const unsigned short* wa = wmix + (size_t)b * 9 * 4096;

    // ---- A ring preload: steps 0..2 (land during prologue staging)
    bf16x8 afp[3][4];
    #pragma unroll
    for (int u0 = 0; u0 < 3; ++u0)
        #pragma unroll
        for (int mt = 0; mt < 4; ++mt)
            afp[u0][mt] = *(const bf16x8*)&wa[(size_t)((u0 * 4 + mt) * 64 + lane) * 8];

    float biasr[4][4];
    #pragma unroll
    for (int mt = 0; mt < 4; ++mt)
        #pragma unroll
        for (int rg = 0; rg < 4; ++rg)
            biasr[mt][rg] = bmix[b * DIM + mt * 16 + q * 4 + rg];

    // ---- prologue: stage rows h0-1 .. h0+4 into slots (rr+7)&7
    {
        f32x4 xv[6][4];
        #pragma unroll
        for (int rr = 0; rr < 6; ++rr) {
            int hin = h0 - 1 + rr;
            bool ok = (hin >= 0) && (hin < HH);    // wave-uniform
            #pragma unroll
            for (int i = 0; i < 4; ++i) {
                f32x4 z = {0.f, 0.f, 0.f, 0.f};
                xv[rr][i] = ok ? *(const f32x4*)&x[(((size_t)b * DIM + 4 * cq + i) * HH + hin) * WW + w0 + 4 * c4] : z;
            }
        }
        float ev[3];
        #pragma unroll
        for (int e = 0; e < 3; ++e) {              // 768 edge items: side*384 + rr*64 + ci
            int item = e * 256 + tid;
            int edge = item >= 384;
            int jj = item - edge * 384;
            int ci = jj & 63, rr = jj >> 6;
            int hin = h0 - 1 + rr;
            int win = edge ? (w0 + 64) : (w0 - 1);
            float v = 0.f;
            if (hin >= 0 && hin < HH && win >= 0 && win < WW)
                v = x[(((size_t)b * DIM + ci) * HH + hin) * WW + win];
            ev[e] = v;
        }
        #pragma unroll
        for (int rr = 0; rr < 6; ++rr) {
            int s = (rr + 7) & 7;
            #pragma unroll
            for (int j = 0; j < 4; ++j) {
                int c = 4 * c4 + 1 + j;
                u32x2 pk;
                pk.x = pack2(xv[rr][0][j], xv[rr][1][j]);
                pk.y = pack2(xv[rr][2][j], xv[rr][3][j]);
                *(u32x2*)&Xs[(s * 66 + c) * 64 + (((cq >> 1) ^ ((c >> 1) & 7)) << 3) + 4 * (cq & 1)] = pk;
            }
        }
        #pragma unroll
        for (int e = 0; e < 3; ++e) {
            int item = e * 256 + tid;
            int edge = item >= 384;
            int jj = item - edge * 384;
            int ci = jj & 63, rr = jj >> 6;
            int s = (rr + 7) & 7;
            int c = edge ? 65 : 0;
            Xs[(s * 66 + c) * 64 + (((ci >> 3) ^ ((c >> 1) & 7)) << 3) + (ci & 7)] = f2bf(ev[e]);
        }
    }

    f32x4 acc[4][4];
    f32x4 zero = {0.f, 0.f, 0.f, 0.f};
    #pragma unroll
    for (int mt = 0; mt < 4; ++mt)
        #pragma unroll
        for (int nt = 0; nt < 4; ++nt) acc[mt][nt] = zero;

    __syncthreads();                               // prologue Xs visible

    #pragma unroll
    for (int t = 0; t < 4; ++t) {
        // ---- issue next-tile loads: new rows h0+4t+5 .. h0+4t+8
        f32x4 nx[4][4];
        float ne[2];
        if (t < 3) {
            #pragma unroll
            for (int rr = 0; rr < 4; ++rr) {
                int hin = h0 + 4 * t + 5 + rr;     // >= 5, only upper bound matters
                bool ok = (hin < HH);              // wave-uniform
                #pragma unroll
                for (int i = 0; i < 4; ++i) {
                    f32x4 z = {0.f, 0.f, 0.f, 0.f};
                    nx[rr][i] = ok ? *(const f32x4*)&x[(((size_t)b * DIM + 4 * cq + i) * HH + hin) * WW + w0 + 4 * c4] : z;
                }
            }
            #pragma unroll
            for (int e = 0; e < 2; ++e) {          // 512 edge items: rr*128 + side*64 + ci
                int item = e * 256 + tid;
                int rr = item >> 7, side = (item >> 6) & 1, ci = item & 63;
                int hin = h0 + 4 * t + 5 + rr;
                int win = side ? (w0 + 64) : (w0 - 1);
                float v = 0.f;
                if (hin < HH && win >= 0 && win < WW)
                    v = x[(((size_t)b * DIM + ci) * HH + hin) * WW + win];
                ne[e] = v;
            }
        }

        // ---- 18 MFMA steps on ring rows (h0+4t-1 .. h0+4t+4)
        #pragma unroll
        for (int st = 0; st < 18; ++st) {
            int tap = st >> 1, sgrp = st & 1;
            int kh = tap / 3, kw = tap - kh * 3;   // compile-time
            int r = (4 * t + 7 + wave + kh) & 7;   // ring slot
            int g = sgrp * 4 + q;
            bf16x8 bfr[4];
            #pragma unroll
            for (int nt = 0; nt < 4; ++nt) {
                int c = nt * 16 + l15 + kw;
                bfr[nt] = *(const bf16x8*)&Xs[(r * 66 + c) * 64 + ((g ^ ((c >> 1) & 7)) << 3)];
            }
            #pragma unroll
            for (int mt = 0; mt < 4; ++mt)
                #pragma unroll
                for (int nt = 0; nt < 4; ++nt)
                    acc[mt][nt] = __builtin_amdgcn_mfma_f32_16x16x32_bf16(
                        afp[st % 3][mt], bfr[nt], acc[mt][nt], 0, 0, 0);
            // continuous A ring refill (same weights every tile -> wrap mod 18)
            #pragma unroll
            for (int mt = 0; mt < 4; ++mt)
                afp[st % 3][mt] = *(const bf16x8*)&wa[(size_t)((((st + 3) % 18) * 4 + mt) * 64 + lane) * 8];

            if (st == 8 && t < 3) {
                // rows +5,+6 -> slots (4t+5)&7,(4t+6)&7: free during tile t
                #pragma unroll
                for (int rr = 0; rr < 2; ++rr) {
                    int s = (4 * t + 5 + rr) & 7;
                    #pragma unroll
                    for (int j = 0; j < 4; ++j) {
                        int c = 4 * c4 + 1 + j;
                        u32x2 pk;
                        pk.x = pack2(nx[rr][0][j], nx[rr][1][j]);
                        pk.y = pack2(nx[rr][2][j], nx[rr][3][j]);
                        *(u32x2*)&Xs[(s * 66 + c) * 64 + (((cq >> 1) ^ ((c >> 1) & 7)) << 3) + 4 * (cq & 1)] = pk;
                    }
                }
                {   // edge e=0 covers rr 0,1
                    int item = tid;
                    int rr = item >> 7, side = (item >> 6) & 1, ci = item & 63;
                    int s = (4 * t + 5 + rr) & 7;
                    int c = side ? 65 : 0;
                    Xs[(s * 66 + c) * 64 + (((ci >> 3) ^ ((c >> 1) & 7)) << 3) + (ci & 7)] = f2bf(ne[0]);
                }
            }
        }

        __syncthreads();                           // all waves done reading tile t

        if (t < 3) {
            // rows +7,+8 -> slots (4t+7)&7,(4t+8)&7: freed by barrier above
            #pragma unroll
            for (int rr = 2; rr < 4; ++rr) {
                int s = (4 * t + 5 + rr) & 7;
                #pragma unroll
                for (int j = 0; j < 4; ++j) {
                    int c = 4 * c4 + 1 + j;
                    u32x2 pk;
                    pk.x = pack2(nx[rr][0][j], nx[rr][1][j]);
                    pk.y = pack2(nx[rr][2][j], nx[rr][3][j]);
                    *(u32x2*)&Xs[(s * 66 + c) * 64 + (((cq >> 1) ^ ((c >> 1) & 7)) << 3) + 4 * (cq & 1)] = pk;
                }
            }
            {   // edge e=1 covers rr 2,3
                int item = 256 + tid;
                int rr = item >> 7, side = (item >> 6) & 1, ci = item & 63;
                int s = (4 * t + 5 + rr) & 7;
                int c = side ? 65 : 0;
                Xs[(s * 66 + c) * 64 + (((ci >> 3) ^ ((c >> 1) & 7)) << 3) + (ci & 7)] = f2bf(ne[1]);
            }
            __syncthreads();                       // new rows visible for tile t+1
        }

        // ---- epilogue tile t (after barriers: store drain hides under next compute)
        int h = h0 + 4 * t + wave;
        #pragma unroll
        for (int mt = 0; mt < 4; ++mt) {
            #pragma unroll
            for (int nt = 0; nt < 4; ++nt) {
                int wcol = w0 + nt * 16 + l15;
                #pragma unroll
                for (int rg = 0; rg < 4; ++rg) {
                    int co = mt * 16 + q * 4 + rg;
                    out[(((size_t)b * DIM + co) * HH + h) * WW + wcol] = acc[mt][nt][rg] + biasr[mt][rg];
                }
                acc[mt][nt] = zero;                // reset for next tile
            }
        }
    }
}

extern "C" void kernel_launch(void* const* d_in, const int* in_sizes, int n_in,
                              void* d_out, int out_size, void* d_ws, size_t ws_size,
                              hipStream_t stream) {
    const float* x   = (const float*)d_in[0];
    const float* att = (const float*)d_in[1];
    const float* wgt = (const float*)d_in[2];
    const float* bia = (const float*)d_in[3];
    float* out = (float*)d_out;

    unsigned short* wmix = (unsigned short*)d_ws;            // 2,359,296 B
    float* bmix = (float*)((char*)d_ws + 2359296);           //     8,192 B

    mix_weights<<<512, 256, 0, stream>>>(wgt, att, wmix);
    mix_bias<<<8, 256, 0, stream>>>(bia, att, bmix);
    conv_mfma<<<512, 256, 0, stream>>>(x, wmix, bmix, out);
}